// Round 10
// baseline (71.314 us; speedup 1.0000x reference)
//
#include <hip/hip_runtime.h>

// Problem constants (from reference)
#define NB 4
#define NN 20000
#define NE 320000
#define HH 128

#define EBLK 64     // histogram blocks (each holds a full 80 KB LDS histogram)
#define HTHR 1024   // threads per histogram block
#define CHUNKS 256  // node chunks for the weighted-sum kernel (1 block/CU)
#define WTHR 512    // threads per wsum block (16 node-groups x 32 lanes)
#define PER 79      // ceil(NN/CHUNKS) nodes per chunk
#define TOTW CHUNKS // completion-counter target

#define RB 79       // reduce_deg blocks doing dinv ( ceil(NN/256) )
#define WARMB 17    // extra blocks that warm Wg/W1/biases into L3

// ws layout (floats):
//   pdeg   [EBLK][NN]   per-block degree partials
//   dinv   [NN]         rsqrt(deg+1)
//   ps     [EBLK][NN]   per-block s partials
//   v      [NB*HH]      pooled feature sums (atomic accum)
//   counter(1 int)      completion counter for last-block MLP
#define OFF_PDEG 0
#define OFF_DINV (EBLK * NN)
#define OFF_PS   (OFF_DINV + NN)
#define OFF_V    (OFF_PS + EBLK * NN)
#define OFF_CNT  (OFF_V + NB * HH)

// --- K1: per-block LDS degree histogram (NO global atomics) ---
__global__ void __launch_bounds__(HTHR) deg_hist_kernel(
        const int* __restrict__ dst, float* __restrict__ pdeg) {
    __shared__ float hist[NN];   // 80 KB
    const int t = threadIdx.x, bk = blockIdx.x;
    for (int i = t; i < NN; i += HTHR) hist[i] = 0.0f;
    __syncthreads();
    for (int e = bk * HTHR + t; e < NE; e += EBLK * HTHR)
        atomicAdd(&hist[dst[e]], 1.0f);          // LDS atomic (ds_add_f32)
    __syncthreads();
    float* out = pdeg + (size_t)bk * NN;
    for (int i = t; i < NN; i += HTHR) out[i] = hist[i];  // coalesced dump
}

// --- K2: dinv[n] = rsqrt(1 + sum_c pdeg[c][n]); block 0 zeroes v+counter;
//         blocks RB.. warm the MLP weights into L3 (they're cold-HBM after
//         the harness poison, and the last-block MLP reads them serially). ---
__global__ void reduce_deg_kernel(const float* __restrict__ pdeg,
                                  float* __restrict__ dinv,
                                  float* __restrict__ v, int* __restrict__ counter,
                                  const float* __restrict__ Wg,
                                  const float* __restrict__ W1,
                                  const float* __restrict__ bg,
                                  const float* __restrict__ b1,
                                  const float* __restrict__ W2) {
    if (blockIdx.x >= RB) {
        // L3 warm: 2*128*128 floats of Wg,W1 (+ biases), kept live via asm.
        const int wt = (blockIdx.x - RB) * 256 + threadIdx.x;  // 0..4351
        float a = 0.0f;
        if (wt < HH * HH / 4) {
            float4 x = ((const float4*)Wg)[wt];
            float4 y = ((const float4*)W1)[wt];
            a = x.x + x.w + y.x + y.w;
        } else if (wt < HH * HH / 4 + HH / 4) {
            const int i = wt - HH * HH / 4;
            float4 x = ((const float4*)bg)[i];
            float4 y = ((const float4*)b1)[i];
            float4 z = ((const float4*)W2)[i];
            a = x.x + y.x + z.x;
        }
        asm volatile("" :: "v"(a));   // keep loads (no DCE)
        return;
    }
    if (blockIdx.x == 0) {
        v[threadIdx.x] = 0.0f;
        v[threadIdx.x + 256] = 0.0f;
        if (threadIdx.x == 0) *counter = 0;
    }
    const int n = blockIdx.x * 256 + threadIdx.x;
    if (n >= NN) return;
    float acc = 1.0f;  // self-loop
    #pragma unroll 8
    for (int c = 0; c < EBLK; ++c) acc += pdeg[(size_t)c * NN + n];
    dinv[n] = rsqrtf(acc);
}

// --- K3: per-block LDS s histogram: s[src] += dinv[dst] ---
__global__ void __launch_bounds__(HTHR) s_hist_kernel(
        const int* __restrict__ src, const int* __restrict__ dst,
        const float* __restrict__ dinv, float* __restrict__ ps) {
    __shared__ float hist[NN];   // 80 KB
    const int t = threadIdx.x, bk = blockIdx.x;
    for (int i = t; i < NN; i += HTHR) hist[i] = 0.0f;
    __syncthreads();
    for (int e = bk * HTHR + t; e < NE; e += EBLK * HTHR)
        atomicAdd(&hist[src[e]], dinv[dst[e]]);  // L2 gather + LDS atomic
    __syncthreads();
    float* out = ps + (size_t)bk * NN;
    for (int i = t; i < NN; i += HTHR) out[i] = hist[i];
}

// --- K4: weighted feature sum (ALL 4 batches per block) + last-block MLP ---
// grid = CHUNKS blocks, 512 threads = 16 node-groups x 32 lanes.
// Per node the b-unrolled loop keeps 4 independent float4 loads in flight;
// the ps prologue is read once per chunk (not once per (chunk,batch)) and is
// parallelized over node x cc-slice so all 512 threads issue 8-deep loads.
__global__ void __launch_bounds__(WTHR) wsum_mlp_kernel(
        const float* __restrict__ fa, const float* __restrict__ fb,
        const float* __restrict__ dinv, const float* __restrict__ ps,
        const float* __restrict__ Wg, const float* __restrict__ bg,
        const float* __restrict__ W1, const float* __restrict__ b1,
        const float* __restrict__ W2, const float* __restrict__ b2,
        float* __restrict__ v, int* __restrict__ counter,
        float* __restrict__ out) {
    __shared__ float wl[PER];
    __shared__ float wpart[PER][8];
    __shared__ float4 smem[WTHR];
    __shared__ int lastflag;
    const int t = threadIdx.x;
    const int c = blockIdx.x;
    const int n0 = c * PER;
    const int n1 = min(NN, n0 + PER);
    const int cnt = n1 - n0;             // may be <= 0 for the last blocks

    if (cnt > 0) {
        // prologue: wpart[i][s] = sum of 8 ps rows (slice s) at node n0+i
        for (int idx = t; idx < cnt * 8; idx += WTHR) {
            const int i = idx >> 3, s = idx & 7;
            const int n = n0 + i;
            float a = 0.0f;
            #pragma unroll
            for (int u = 0; u < 8; ++u) a += ps[(size_t)(s * 8 + u) * NN + n];
            wpart[i][s] = a;
        }
        __syncthreads();
        for (int i = t; i < cnt; i += WTHR) {
            float a = 0.0f;
            #pragma unroll
            for (int s = 0; s < 8; ++s) a += wpart[i][s];
            const float di = dinv[n0 + i];
            wl[i] = di * (di + a);
        }
        __syncthreads();

        const int g = t >> 5;        // node subgroup 0..15
        const int q = t & 31;
        const float* base = (q < 16) ? (fa + (size_t)q * 4)
                                     : (fb + (size_t)(q - 16) * 4);

        float4 acc[NB];
        #pragma unroll
        for (int b = 0; b < NB; ++b) acc[b] = make_float4(0.f, 0.f, 0.f, 0.f);

        for (int n = n0 + g; n < n1; n += 16) {
            const float wn = wl[n - n0];
            #pragma unroll
            for (int b = 0; b < NB; ++b) {
                float4 x = *reinterpret_cast<const float4*>(
                    base + ((size_t)b * NN + n) * 64);
                acc[b].x += wn * x.x; acc[b].y += wn * x.y;
                acc[b].z += wn * x.z; acc[b].w += wn * x.w;
            }
        }

        #pragma unroll
        for (int b = 0; b < NB; ++b) {
            smem[t] = acc[b];
            __syncthreads();
            if (t < 32) {    // wave 0 issues ALL of this block's v-atomics
                float4 r = smem[t];
                #pragma unroll
                for (int gg = 1; gg < 16; ++gg) {
                    float4 o = smem[gg * 32 + t];
                    r.x += o.x; r.y += o.y; r.z += o.z; r.w += o.w;
                }
                const int k = (t < 16) ? t * 4 : 64 + (t - 16) * 4;
                float* vb = v + b * HH + k;
                atomicAdd(vb + 0, r.x);
                atomicAdd(vb + 1, r.y);
                atomicAdd(vb + 2, r.z);
                atomicAdd(vb + 3, r.w);
            }
            __syncthreads();
        }
    }

    if (t == 0) {
        // wave 0 waits for its own v-atomics to reach the coherent point,
        // then publishes completion. No cache flush / threadfence needed.
        asm volatile("s_waitcnt vmcnt(0)" ::: "memory");
        int old = atomicAdd(counter, 1);
        lastflag = (old == TOTW - 1);
    }
    __syncthreads();
    if (!lastflag) return;

    // ---- last block: read v coherently and run the MLP head ----
    __shared__ float xs[NB][HH];
    __shared__ float ys[NB][HH];
    __shared__ float red[NB][HH];
    const int bb = t >> 7;           // 0..3
    const int kk = t & (HH - 1);     // 0..127

    float val = atomicAdd(&v[t], 0.0f);   // coherent RMW read of v[bb*HH+kk]
    xs[bb][kk] = val * (1.0f / NN);
    __syncthreads();

    // layer 1: pooled = xs @ Wg + bg  (weights L3-warm from reduce_deg)
    float a1 = bg[kk];
    #pragma unroll 16
    for (int j = 0; j < HH; ++j) a1 += xs[bb][j] * Wg[j * HH + kk];
    ys[bb][kk] = a1;
    __syncthreads();

    // layer 2: hid = relu(ys @ W1 + b1), fold W2 scale
    float a2 = b1[kk];
    #pragma unroll 16
    for (int j = 0; j < HH; ++j) a2 += ys[bb][j] * W1[j * HH + kk];
    a2 = fmaxf(a2, 0.0f);
    red[bb][kk] = a2 * W2[kk];
    __syncthreads();

    // tree-reduce 128 -> 1 per batch
    #pragma unroll
    for (int off = HH / 2; off > 0; off >>= 1) {
        if (kk < off) red[bb][kk] += red[bb][kk + off];
        __syncthreads();
    }
    if (kk == 0) out[bb] = red[bb][0] + b2[0];
}

extern "C" void kernel_launch(void* const* d_in, const int* in_sizes, int n_in,
                              void* d_out, int out_size, void* d_ws, size_t ws_size,
                              hipStream_t stream) {
    const float* fa = (const float*)d_in[0];   // [B,N,64]
    const float* fb = (const float*)d_in[1];   // [B,N,64]
    const int*   ei = (const int*)d_in[2];     // [2,E]
    const float* Wg = (const float*)d_in[3];   // [H,H]
    const float* bg = (const float*)d_in[4];   // [H]
    const float* W1 = (const float*)d_in[5];   // [H,H]
    const float* b1 = (const float*)d_in[6];   // [H]
    const float* W2 = (const float*)d_in[7];   // [H,1]
    const float* b2 = (const float*)d_in[8];   // [1]
    float* out = (float*)d_out;

    const int* src = ei;
    const int* dst = ei + NE;

    float* ws   = (float*)d_ws;
    float* pdeg = ws + OFF_PDEG;
    float* dinv = ws + OFF_DINV;
    float* ps   = ws + OFF_PS;
    float* v    = ws + OFF_V;
    int* counter = (int*)(ws + OFF_CNT);

    deg_hist_kernel<<<EBLK, HTHR, 0, stream>>>(dst, pdeg);

    reduce_deg_kernel<<<RB + WARMB, 256, 0, stream>>>(pdeg, dinv, v, counter,
                                                      Wg, W1, bg, b1, W2);

    s_hist_kernel<<<EBLK, HTHR, 0, stream>>>(src, dst, dinv, ps);

    wsum_mlp_kernel<<<CHUNKS, WTHR, 0, stream>>>(fa, fb, dinv, ps,
                                                 Wg, bg, W1, b1, W2, b2,
                                                 v, counter, out);
}

// Round 12
// 54.990 us; speedup vs baseline: 1.2969x; 1.2969x over previous
//
#include <hip/hip_runtime.h>

// Problem constants (from reference)
#define NB 4
#define NN 20000
#define NE 320000
#define HH 128

#define EBLK 64     // histogram blocks (each holds a full 80 KB LDS histogram)
#define HTHR 1024   // threads per histogram block
#define CHUNKS 256  // node chunks for the weighted-sum kernel (1 block/CU)
#define WTHR 512    // threads per wsum block (16 node-groups x 32 lanes)
#define PER 79      // ceil(NN/CHUNKS) nodes per chunk
#define TOTW CHUNKS // completion-counter target
#define NSEC 8      // v sectors (cuts per-address atomic contention 256 -> ~32)

#define RB 79       // reduce_deg blocks ( ceil(NN/256) )

// ws layout (floats):
//   pdeg   [EBLK][NN]     per-block degree partials
//   dinv   [NN]           rsqrt(deg+1)
//   ps     [EBLK][NN]     per-block s partials
//   v      [NSEC][NB*HH]  pooled feature sums (sectored atomic accum)
//   counter(1 int)        completion counter for last-block MLP
#define OFF_PDEG 0
#define OFF_DINV (EBLK * NN)
#define OFF_PS   (OFF_DINV + NN)
#define OFF_V    (OFF_PS + EBLK * NN)
#define OFF_CNT  (OFF_V + NSEC * NB * HH)

// --- K1: per-block LDS degree histogram (NO global atomics) ---
__global__ void __launch_bounds__(HTHR) deg_hist_kernel(
        const int* __restrict__ dst, float* __restrict__ pdeg) {
    __shared__ float hist[NN];   // 80 KB
    const int t = threadIdx.x, bk = blockIdx.x;
    for (int i = t; i < NN; i += HTHR) hist[i] = 0.0f;
    __syncthreads();
    for (int e = bk * HTHR + t; e < NE; e += EBLK * HTHR)
        atomicAdd(&hist[dst[e]], 1.0f);          // LDS atomic (ds_add_f32)
    __syncthreads();
    float* out = pdeg + (size_t)bk * NN;
    for (int i = t; i < NN; i += HTHR) out[i] = hist[i];  // coalesced dump
}

// --- K2: dinv[n] = rsqrt(1 + sum_c pdeg[c][n]); block 0 zeroes v+counter.
//         (Plain stores are safe: the kernel boundary flushes L2 before K4.) ---
__global__ void reduce_deg_kernel(const float* __restrict__ pdeg,
                                  float* __restrict__ dinv,
                                  float* __restrict__ v, int* __restrict__ counter) {
    if (blockIdx.x == 0) {
        #pragma unroll
        for (int u = 0; u < NSEC * NB * HH / 256; ++u)
            v[u * 256 + threadIdx.x] = 0.0f;
        if (threadIdx.x == 0) *counter = 0;
    }
    const int n = blockIdx.x * 256 + threadIdx.x;
    if (n >= NN) return;
    float acc = 1.0f;  // self-loop
    #pragma unroll 8
    for (int c = 0; c < EBLK; ++c) acc += pdeg[(size_t)c * NN + n];
    dinv[n] = rsqrtf(acc);
}

// --- K3: per-block LDS s histogram: s[src] += dinv[dst] ---
__global__ void __launch_bounds__(HTHR) s_hist_kernel(
        const int* __restrict__ src, const int* __restrict__ dst,
        const float* __restrict__ dinv, float* __restrict__ ps) {
    __shared__ float hist[NN];   // 80 KB
    const int t = threadIdx.x, bk = blockIdx.x;
    for (int i = t; i < NN; i += HTHR) hist[i] = 0.0f;
    __syncthreads();
    for (int e = bk * HTHR + t; e < NE; e += EBLK * HTHR)
        atomicAdd(&hist[src[e]], dinv[dst[e]]);  // L2 gather + LDS atomic
    __syncthreads();
    float* out = ps + (size_t)bk * NN;
    for (int i = t; i < NN; i += HTHR) out[i] = hist[i];
}

// --- K4: weighted feature sum (ALL 4 batches per block) + last-block MLP ---
// grid = CHUNKS blocks, 512 threads = 16 node-groups x 32 lanes.
// 4-deep node unroll x 4 batches = 16 independent float4 loads in flight.
// v is sectored: block c accumulates into sector c&7 (per-address atomic
// chain ~32 instead of ~254); the last block sums the 8 sectors.
__global__ void __launch_bounds__(WTHR) wsum_mlp_kernel(
        const float* __restrict__ fa, const float* __restrict__ fb,
        const float* __restrict__ dinv, const float* __restrict__ ps,
        const float* __restrict__ Wg, const float* __restrict__ bg,
        const float* __restrict__ W1, const float* __restrict__ b1,
        const float* __restrict__ W2, const float* __restrict__ b2,
        float* __restrict__ v, int* __restrict__ counter,
        float* __restrict__ out) {
    __shared__ float wl[PER];
    __shared__ float wpart[PER][8];
    __shared__ float4 smem[WTHR];
    __shared__ int lastflag;
    const int t = threadIdx.x;
    const int c = blockIdx.x;
    const int n0 = c * PER;
    const int n1 = min(NN, n0 + PER);
    const int cnt = n1 - n0;             // may be <= 0 for the last blocks
    float* vsec = v + (size_t)(c & (NSEC - 1)) * (NB * HH);

    if (cnt > 0) {
        // prologue: wpart[i][s] = sum of 8 ps rows (slice s) at node n0+i
        for (int idx = t; idx < cnt * 8; idx += WTHR) {
            const int i = idx >> 3, s = idx & 7;
            const int n = n0 + i;
            float a = 0.0f;
            #pragma unroll
            for (int u = 0; u < 8; ++u) a += ps[(size_t)(s * 8 + u) * NN + n];
            wpart[i][s] = a;
        }
        __syncthreads();
        for (int i = t; i < cnt; i += WTHR) {
            float a = 0.0f;
            #pragma unroll
            for (int s = 0; s < 8; ++s) a += wpart[i][s];
            const float di = dinv[n0 + i];
            wl[i] = di * (di + a);
        }
        __syncthreads();

        const int g = t >> 5;        // node subgroup 0..15
        const int q = t & 31;
        const float* base = (q < 16) ? (fa + (size_t)q * 4)
                                     : (fb + (size_t)(q - 16) * 4);

        float4 acc[NB];
        #pragma unroll
        for (int b = 0; b < NB; ++b) acc[b] = make_float4(0.f, 0.f, 0.f, 0.f);

        int n = n0 + g;
        // main: 4 nodes x 4 batches = 16 independent float4 loads in flight
        for (; n + 48 < n1; n += 64) {
            const float w0 = wl[n - n0];
            const float w1 = wl[n + 16 - n0];
            const float w2 = wl[n + 32 - n0];
            const float w3 = wl[n + 48 - n0];
            #pragma unroll
            for (int b = 0; b < NB; ++b) {
                const float* p = base + ((size_t)b * NN + n) * 64;
                float4 x0 = *reinterpret_cast<const float4*>(p);
                float4 x1 = *reinterpret_cast<const float4*>(p + 16 * 64);
                float4 x2 = *reinterpret_cast<const float4*>(p + 32 * 64);
                float4 x3 = *reinterpret_cast<const float4*>(p + 48 * 64);
                acc[b].x += w0 * x0.x + w1 * x1.x + w2 * x2.x + w3 * x3.x;
                acc[b].y += w0 * x0.y + w1 * x1.y + w2 * x2.y + w3 * x3.y;
                acc[b].z += w0 * x0.z + w1 * x1.z + w2 * x2.z + w3 * x3.z;
                acc[b].w += w0 * x0.w + w1 * x1.w + w2 * x2.w + w3 * x3.w;
            }
        }
        for (; n < n1; n += 16) {     // remainder (<= 3 nodes per g)
            const float wn = wl[n - n0];
            #pragma unroll
            for (int b = 0; b < NB; ++b) {
                float4 x = *reinterpret_cast<const float4*>(
                    base + ((size_t)b * NN + n) * 64);
                acc[b].x += wn * x.x; acc[b].y += wn * x.y;
                acc[b].z += wn * x.z; acc[b].w += wn * x.w;
            }
        }

        #pragma unroll
        for (int b = 0; b < NB; ++b) {
            smem[t] = acc[b];
            __syncthreads();
            if (t < 32) {    // wave 0 issues ALL of this block's v-atomics
                float4 r = smem[t];
                #pragma unroll
                for (int gg = 1; gg < 16; ++gg) {
                    float4 o = smem[gg * 32 + t];
                    r.x += o.x; r.y += o.y; r.z += o.z; r.w += o.w;
                }
                const int k = (t < 16) ? t * 4 : 64 + (t - 16) * 4;
                float* vb = vsec + b * HH + k;
                atomicAdd(vb + 0, r.x);
                atomicAdd(vb + 1, r.y);
                atomicAdd(vb + 2, r.z);
                atomicAdd(vb + 3, r.w);
            }
            __syncthreads();
        }
    }

    if (t == 0) {
        // wave 0 waits for its own v-atomics to reach the coherent point,
        // then publishes completion. No cache flush / threadfence needed.
        asm volatile("s_waitcnt vmcnt(0)" ::: "memory");
        int old = atomicAdd(counter, 1);
        lastflag = (old == TOTW - 1);
    }
    __syncthreads();
    if (!lastflag) return;

    // ---- last block: read sectored v coherently and run the MLP head ----
    __shared__ float xs[NB][HH];
    __shared__ float ys[NB][HH];
    __shared__ float red[NB][HH];
    const int bb = t >> 7;           // 0..3
    const int kk = t & (HH - 1);     // 0..127

    float val = 0.0f;
    #pragma unroll
    for (int s = 0; s < NSEC; ++s)
        val += atomicAdd(&v[s * (NB * HH) + t], 0.0f);  // coherent RMW reads
    xs[bb][kk] = val * (1.0f / NN);
    __syncthreads();

    // layer 1: pooled = xs @ Wg + bg
    float a1 = bg[kk];
    #pragma unroll 8
    for (int j = 0; j < HH; ++j) a1 += xs[bb][j] * Wg[j * HH + kk];
    ys[bb][kk] = a1;
    __syncthreads();

    // layer 2: hid = relu(ys @ W1 + b1), fold W2 scale
    float a2 = b1[kk];
    #pragma unroll 8
    for (int j = 0; j < HH; ++j) a2 += ys[bb][j] * W1[j * HH + kk];
    a2 = fmaxf(a2, 0.0f);
    red[bb][kk] = a2 * W2[kk];
    __syncthreads();

    // tree-reduce 128 -> 1 per batch
    #pragma unroll
    for (int off = HH / 2; off > 0; off >>= 1) {
        if (kk < off) red[bb][kk] += red[bb][kk + off];
        __syncthreads();
    }
    if (kk == 0) out[bb] = red[bb][0] + b2[0];
}

extern "C" void kernel_launch(void* const* d_in, const int* in_sizes, int n_in,
                              void* d_out, int out_size, void* d_ws, size_t ws_size,
                              hipStream_t stream) {
    const float* fa = (const float*)d_in[0];   // [B,N,64]
    const float* fb = (const float*)d_in[1];   // [B,N,64]
    const int*   ei = (const int*)d_in[2];     // [2,E]
    const float* Wg = (const float*)d_in[3];   // [H,H]
    const float* bg = (const float*)d_in[4];   // [H]
    const float* W1 = (const float*)d_in[5];   // [H,H]
    const float* b1 = (const float*)d_in[6];   // [H]
    const float* W2 = (const float*)d_in[7];   // [H,1]
    const float* b2 = (const float*)d_in[8];   // [1]
    float* out = (float*)d_out;

    const int* src = ei;
    const int* dst = ei + NE;

    float* ws   = (float*)d_ws;
    float* pdeg = ws + OFF_PDEG;
    float* dinv = ws + OFF_DINV;
    float* ps   = ws + OFF_PS;
    float* v    = ws + OFF_V;
    int* counter = (int*)(ws + OFF_CNT);

    deg_hist_kernel<<<EBLK, HTHR, 0, stream>>>(dst, pdeg);

    reduce_deg_kernel<<<RB, 256, 0, stream>>>(pdeg, dinv, v, counter);

    s_hist_kernel<<<EBLK, HTHR, 0, stream>>>(src, dst, dinv, ps);

    wsum_mlp_kernel<<<CHUNKS, WTHR, 0, stream>>>(fa, fb, dinv, ps,
                                                 Wg, bg, W1, b1, W2, b2,
                                                 v, counter, out);
}

// Round 13
// 54.234 us; speedup vs baseline: 1.3149x; 1.0139x over previous
//
#include <hip/hip_runtime.h>

// Problem constants (from reference)
#define NB 4
#define NN 20000
#define NE 320000
#define HH 128

#define EBLK 64     // histogram blocks (each holds a full 80 KB LDS histogram)
#define HTHR 1024   // threads per histogram block
#define CHUNKS 256  // node chunks for the weighted-sum kernel (1 block/CU)
#define WTHR 512    // threads per wsum block (16 node-groups x 32 lanes)
#define PER 79      // ceil(NN/CHUNKS) nodes per chunk
#define TOTW CHUNKS // completion-counter target
#define NSEC 8      // v sectors (cuts per-address atomic contention 256 -> ~32)

#define RB 79       // reduce_deg blocks ( ceil(NN/256) )

// ws layout (floats):
//   pdeg   [EBLK][NN]     per-block degree partials
//   dinv   [NN]           rsqrt(deg+1)
//   ps     [EBLK][NN]     per-block s partials
//   v      [NSEC][NB*HH]  pooled feature sums (sectored atomic accum)
//   counter(1 int)        completion counter for last-block MLP
#define OFF_PDEG 0
#define OFF_DINV (EBLK * NN)
#define OFF_PS   (OFF_DINV + NN)
#define OFF_V    (OFF_PS + EBLK * NN)
#define OFF_CNT  (OFF_V + NSEC * NB * HH)

// --- K1: per-block LDS degree histogram (NO global atomics) ---
__global__ void __launch_bounds__(HTHR) deg_hist_kernel(
        const int* __restrict__ dst, float* __restrict__ pdeg) {
    __shared__ float hist[NN];   // 80 KB
    const int t = threadIdx.x, bk = blockIdx.x;
    for (int i = t; i < NN; i += HTHR) hist[i] = 0.0f;
    __syncthreads();
    for (int e = bk * HTHR + t; e < NE; e += EBLK * HTHR)
        atomicAdd(&hist[dst[e]], 1.0f);          // LDS atomic (ds_add_f32)
    __syncthreads();
    float* out = pdeg + (size_t)bk * NN;
    for (int i = t; i < NN; i += HTHR) out[i] = hist[i];  // coalesced dump
}

// --- K2: dinv[n] = rsqrt(1 + sum_c pdeg[c][n]); block 0 zeroes v+counter.
//         (Plain stores are safe: the kernel boundary flushes L2 before K4.) ---
__global__ void reduce_deg_kernel(const float* __restrict__ pdeg,
                                  float* __restrict__ dinv,
                                  float* __restrict__ v, int* __restrict__ counter) {
    if (blockIdx.x == 0) {
        #pragma unroll
        for (int u = 0; u < NSEC * NB * HH / 256; ++u)
            v[u * 256 + threadIdx.x] = 0.0f;
        if (threadIdx.x == 0) *counter = 0;
    }
    const int n = blockIdx.x * 256 + threadIdx.x;
    if (n >= NN) return;
    float acc = 1.0f;  // self-loop
    #pragma unroll 8
    for (int c = 0; c < EBLK; ++c) acc += pdeg[(size_t)c * NN + n];
    dinv[n] = rsqrtf(acc);
}

// --- K3: per-block LDS s histogram: s[src] += dinv[dst] ---
__global__ void __launch_bounds__(HTHR) s_hist_kernel(
        const int* __restrict__ src, const int* __restrict__ dst,
        const float* __restrict__ dinv, float* __restrict__ ps) {
    __shared__ float hist[NN];   // 80 KB
    const int t = threadIdx.x, bk = blockIdx.x;
    for (int i = t; i < NN; i += HTHR) hist[i] = 0.0f;
    __syncthreads();
    for (int e = bk * HTHR + t; e < NE; e += EBLK * HTHR)
        atomicAdd(&hist[src[e]], dinv[dst[e]]);  // L2 gather + LDS atomic
    __syncthreads();
    float* out = ps + (size_t)bk * NN;
    for (int i = t; i < NN; i += HTHR) out[i] = hist[i];
}

// --- K4: weighted feature sum (ALL 4 batches per block) + last-block MLP ---
// grid = CHUNKS blocks, 512 threads = 16 node-groups x 32 lanes.
// 4-deep node unroll x 4 batches = 16 independent float4 loads in flight.
// v is sectored: block c accumulates into sector c&7 (per-address atomic
// chain ~32 instead of ~254); the last block sums the 8 sectors.
__global__ void __launch_bounds__(WTHR) wsum_mlp_kernel(
        const float* __restrict__ fa, const float* __restrict__ fb,
        const float* __restrict__ dinv, const float* __restrict__ ps,
        const float* __restrict__ Wg, const float* __restrict__ bg,
        const float* __restrict__ W1, const float* __restrict__ b1,
        const float* __restrict__ W2, const float* __restrict__ b2,
        float* __restrict__ v, int* __restrict__ counter,
        float* __restrict__ out) {
    __shared__ float wl[PER];
    __shared__ float wpart[PER][8];
    __shared__ float4 smem[WTHR];
    __shared__ int lastflag;
    const int t = threadIdx.x;
    const int c = blockIdx.x;
    const int n0 = c * PER;
    const int n1 = min(NN, n0 + PER);
    const int cnt = n1 - n0;             // may be <= 0 for the last blocks
    float* vsec = v + (size_t)(c & (NSEC - 1)) * (NB * HH);

    if (cnt > 0) {
        // prologue: wpart[i][s] = sum of 8 ps rows (slice s) at node n0+i
        for (int idx = t; idx < cnt * 8; idx += WTHR) {
            const int i = idx >> 3, s = idx & 7;
            const int n = n0 + i;
            float a = 0.0f;
            #pragma unroll
            for (int u = 0; u < 8; ++u) a += ps[(size_t)(s * 8 + u) * NN + n];
            wpart[i][s] = a;
        }
        __syncthreads();
        for (int i = t; i < cnt; i += WTHR) {
            float a = 0.0f;
            #pragma unroll
            for (int s = 0; s < 8; ++s) a += wpart[i][s];
            const float di = dinv[n0 + i];
            wl[i] = di * (di + a);
        }
        __syncthreads();

        const int g = t >> 5;        // node subgroup 0..15
        const int q = t & 31;
        const float* base = (q < 16) ? (fa + (size_t)q * 4)
                                     : (fb + (size_t)(q - 16) * 4);

        float4 acc[NB];
        #pragma unroll
        for (int b = 0; b < NB; ++b) acc[b] = make_float4(0.f, 0.f, 0.f, 0.f);

        int n = n0 + g;
        // main: 4 nodes x 4 batches = 16 independent float4 loads in flight
        for (; n + 48 < n1; n += 64) {
            const float w0 = wl[n - n0];
            const float w1 = wl[n + 16 - n0];
            const float w2 = wl[n + 32 - n0];
            const float w3 = wl[n + 48 - n0];
            #pragma unroll
            for (int b = 0; b < NB; ++b) {
                const float* p = base + ((size_t)b * NN + n) * 64;
                float4 x0 = *reinterpret_cast<const float4*>(p);
                float4 x1 = *reinterpret_cast<const float4*>(p + 16 * 64);
                float4 x2 = *reinterpret_cast<const float4*>(p + 32 * 64);
                float4 x3 = *reinterpret_cast<const float4*>(p + 48 * 64);
                acc[b].x += w0 * x0.x + w1 * x1.x + w2 * x2.x + w3 * x3.x;
                acc[b].y += w0 * x0.y + w1 * x1.y + w2 * x2.y + w3 * x3.y;
                acc[b].z += w0 * x0.z + w1 * x1.z + w2 * x2.z + w3 * x3.z;
                acc[b].w += w0 * x0.w + w1 * x1.w + w2 * x2.w + w3 * x3.w;
            }
        }
        for (; n < n1; n += 16) {     // remainder (<= 3 nodes per g)
            const float wn = wl[n - n0];
            #pragma unroll
            for (int b = 0; b < NB; ++b) {
                float4 x = *reinterpret_cast<const float4*>(
                    base + ((size_t)b * NN + n) * 64);
                acc[b].x += wn * x.x; acc[b].y += wn * x.y;
                acc[b].z += wn * x.z; acc[b].w += wn * x.w;
            }
        }

        #pragma unroll
        for (int b = 0; b < NB; ++b) {
            smem[t] = acc[b];
            __syncthreads();
            if (t < 32) {    // wave 0 issues ALL of this block's v-atomics
                float4 r = smem[t];
                #pragma unroll
                for (int gg = 1; gg < 16; ++gg) {
                    float4 o = smem[gg * 32 + t];
                    r.x += o.x; r.y += o.y; r.z += o.z; r.w += o.w;
                }
                const int k = (t < 16) ? t * 4 : 64 + (t - 16) * 4;
                float* vb = vsec + b * HH + k;
                atomicAdd(vb + 0, r.x);
                atomicAdd(vb + 1, r.y);
                atomicAdd(vb + 2, r.z);
                atomicAdd(vb + 3, r.w);
            }
            __syncthreads();
        }
    }

    if (t == 0) {
        // wave 0 waits for its own v-atomics to reach the coherent point,
        // then publishes completion. No cache flush / threadfence needed.
        asm volatile("s_waitcnt vmcnt(0)" ::: "memory");
        int old = atomicAdd(counter, 1);
        lastflag = (old == TOTW - 1);
    }
    __syncthreads();
    if (!lastflag) return;

    // ---- last block: read sectored v coherently and run the MLP head ----
    __shared__ float xs[NB][HH];
    __shared__ float ys[NB][HH];
    __shared__ float red[NB][HH];
    const int bb = t >> 7;           // 0..3
    const int kk = t & (HH - 1);     // 0..127

    float val = 0.0f;
    #pragma unroll
    for (int s = 0; s < NSEC; ++s)
        val += atomicAdd(&v[s * (NB * HH) + t], 0.0f);  // coherent RMW reads
    xs[bb][kk] = val * (1.0f / NN);
    __syncthreads();

    // layer 1: pooled = xs @ Wg + bg
    float a1 = bg[kk];
    #pragma unroll 8
    for (int j = 0; j < HH; ++j) a1 += xs[bb][j] * Wg[j * HH + kk];
    ys[bb][kk] = a1;
    __syncthreads();

    // layer 2: hid = relu(ys @ W1 + b1), fold W2 scale
    float a2 = b1[kk];
    #pragma unroll 8
    for (int j = 0; j < HH; ++j) a2 += ys[bb][j] * W1[j * HH + kk];
    a2 = fmaxf(a2, 0.0f);
    red[bb][kk] = a2 * W2[kk];
    __syncthreads();

    // tree-reduce 128 -> 1 per batch
    #pragma unroll
    for (int off = HH / 2; off > 0; off >>= 1) {
        if (kk < off) red[bb][kk] += red[bb][kk + off];
        __syncthreads();
    }
    if (kk == 0) out[bb] = red[bb][0] + b2[0];
}

extern "C" void kernel_launch(void* const* d_in, const int* in_sizes, int n_in,
                              void* d_out, int out_size, void* d_ws, size_t ws_size,
                              hipStream_t stream) {
    const float* fa = (const float*)d_in[0];   // [B,N,64]
    const float* fb = (const float*)d_in[1];   // [B,N,64]
    const int*   ei = (const int*)d_in[2];     // [2,E]
    const float* Wg = (const float*)d_in[3];   // [H,H]
    const float* bg = (const float*)d_in[4];   // [H]
    const float* W1 = (const float*)d_in[5];   // [H,H]
    const float* b1 = (const float*)d_in[6];   // [H]
    const float* W2 = (const float*)d_in[7];   // [H,1]
    const float* b2 = (const float*)d_in[8];   // [1]
    float* out = (float*)d_out;

    const int* src = ei;
    const int* dst = ei + NE;

    float* ws   = (float*)d_ws;
    float* pdeg = ws + OFF_PDEG;
    float* dinv = ws + OFF_DINV;
    float* ps   = ws + OFF_PS;
    float* v    = ws + OFF_V;
    int* counter = (int*)(ws + OFF_CNT);

    deg_hist_kernel<<<EBLK, HTHR, 0, stream>>>(dst, pdeg);

    reduce_deg_kernel<<<RB, 256, 0, stream>>>(pdeg, dinv, v, counter);

    s_hist_kernel<<<EBLK, HTHR, 0, stream>>>(src, dst, dinv, ps);

    wsum_mlp_kernel<<<CHUNKS, WTHR, 0, stream>>>(fa, fb, dinv, ps,
                                                 Wg, bg, W1, b1, W2, b2,
                                                 v, counter, out);
}

// Round 14
// 51.130 us; speedup vs baseline: 1.3948x; 1.0607x over previous
//
#include <hip/hip_runtime.h>

// Problem constants (from reference)
#define NB 4
#define NN 20000
#define NE 320000
#define HH 128

#define EBLK 64     // histogram blocks (each holds a full 80 KB LDS histogram)
#define HTHR 1024   // threads per histogram block
#define CHUNKS 256  // node chunks for the weighted-sum kernel
#define WTHR 512    // threads per wsum block (16 node-groups x 32 lanes)
#define PER 79      // ceil(NN/CHUNKS) nodes per chunk
#define NSEC 8      // v sectors (cuts per-address atomic contention)

#define RB 79       // reduce_deg blocks ( ceil(NN/256) )

// ws layout (floats):
//   pdeg   [EBLK][NN]     per-block degree partials
//   dinv   [NN]           rsqrt(deg+1)
//   ps     [EBLK][NN]     per-block s partials
//   v      [NSEC][NB*HH]  pooled feature sums (sectored atomic accum)
//   cnts   [9] ints       sub[8] sector counters + master
#define OFF_PDEG 0
#define OFF_DINV (EBLK * NN)
#define OFF_PS   (OFF_DINV + NN)
#define OFF_V    (OFF_PS + EBLK * NN)
#define OFF_CNT  (OFF_V + NSEC * NB * HH)

// --- K1: per-block LDS degree histogram (NO global atomics) ---
__global__ void __launch_bounds__(HTHR) deg_hist_kernel(
        const int* __restrict__ dst, float* __restrict__ pdeg) {
    __shared__ float hist[NN];   // 80 KB
    const int t = threadIdx.x, bk = blockIdx.x;
    for (int i = t; i < NN; i += HTHR) hist[i] = 0.0f;
    __syncthreads();
    for (int e = bk * HTHR + t; e < NE; e += EBLK * HTHR)
        atomicAdd(&hist[dst[e]], 1.0f);          // LDS atomic (ds_add_f32)
    __syncthreads();
    float* out = pdeg + (size_t)bk * NN;
    for (int i = t; i < NN; i += HTHR) out[i] = hist[i];  // coalesced dump
}

// --- K2: dinv[n] = rsqrt(1 + sum_c pdeg[c][n]); block 0 zeroes v + counters.
//         (Plain stores are safe: the kernel boundary flushes L2 before K4.) ---
__global__ void reduce_deg_kernel(const float* __restrict__ pdeg,
                                  float* __restrict__ dinv,
                                  float* __restrict__ v, int* __restrict__ cnts) {
    if (blockIdx.x == 0) {
        #pragma unroll
        for (int u = 0; u < NSEC * NB * HH / 256; ++u)
            v[u * 256 + threadIdx.x] = 0.0f;
        if (threadIdx.x < 9) cnts[threadIdx.x] = 0;   // sub[8] + master
    }
    const int n = blockIdx.x * 256 + threadIdx.x;
    if (n >= NN) return;
    float acc = 1.0f;  // self-loop
    #pragma unroll 8
    for (int c = 0; c < EBLK; ++c) acc += pdeg[(size_t)c * NN + n];
    dinv[n] = rsqrtf(acc);
}

// --- K3: per-block LDS s histogram: s[src] += dinv[dst] ---
__global__ void __launch_bounds__(HTHR) s_hist_kernel(
        const int* __restrict__ src, const int* __restrict__ dst,
        const float* __restrict__ dinv, float* __restrict__ ps) {
    __shared__ float hist[NN];   // 80 KB
    const int t = threadIdx.x, bk = blockIdx.x;
    for (int i = t; i < NN; i += HTHR) hist[i] = 0.0f;
    __syncthreads();
    for (int e = bk * HTHR + t; e < NE; e += EBLK * HTHR)
        atomicAdd(&hist[src[e]], dinv[dst[e]]);  // L2 gather + LDS atomic
    __syncthreads();
    float* out = ps + (size_t)bk * NN;
    for (int i = t; i < NN; i += HTHR) out[i] = hist[i];
}

// --- K4: weighted feature sum (workers, blocks 1..256) + MLP block (block 0).
// Workers: 16 node-groups x 32 lanes, 4-deep node unroll x 4 batches = 16
// independent float4 loads in flight; v sectored by (chunk&7).
// Completion: hierarchical counters -- sub[c&7] (32 blocks each), 32nd
// incrementer bumps master. Max same-address chain: 32 instead of 256.
// Block 0: prefetches Wg into LDS (warms W1 to L3) while workers run, spins
// on master with s_sleep, then runs both GEMV layers from LDS.
__global__ void __launch_bounds__(WTHR) wsum_mlp_kernel(
        const float* __restrict__ fa, const float* __restrict__ fb,
        const float* __restrict__ dinv, const float* __restrict__ ps,
        const float* __restrict__ Wg, const float* __restrict__ bg,
        const float* __restrict__ W1, const float* __restrict__ b1,
        const float* __restrict__ W2, const float* __restrict__ b2,
        float* __restrict__ v, int* __restrict__ cnts,
        float* __restrict__ out) {
    __shared__ float WL[HH * HH];        // 64 KB weight tile (block 0 only)
    __shared__ float xs[NB * HH];
    __shared__ float ys[NB * HH];
    __shared__ float red[NB * HH];
    __shared__ float wl[PER];
    __shared__ float wpart[PER][8];
    __shared__ float4 smem[WTHR];
    int* sub = cnts;
    int* master = cnts + 8;
    const int t = threadIdx.x;

    if (blockIdx.x == 0) {
        // ---- MLP block: prefetch Wg -> LDS, warm W1 -> L3, spin, compute ----
        const float4* wgv = (const float4*)Wg;
        const float4* w1v = (const float4*)W1;
        float4* wlv = (float4*)WL;
        float warm = 0.0f;
        for (int i = t; i < HH * HH / 4; i += WTHR) {
            wlv[i] = wgv[i];                 // Wg -> LDS
            float4 y = w1v[i];               // W1 -> L3 (kept live, no DCE)
            warm += y.x + y.w;
        }
        asm volatile("" :: "v"(warm));
        if (t == 0) {
            while (atomicAdd(master, 0) < NSEC) __builtin_amdgcn_s_sleep(8);
        }
        __syncthreads();

        // sector-reduce v (8 independent coherent RMW reads in flight)
        float val = 0.0f;
        #pragma unroll
        for (int s = 0; s < NSEC; ++s)
            val += atomicAdd(&v[s * (NB * HH) + t], 0.0f);
        xs[t] = val * (1.0f / NN);
        __syncthreads();

        const int bb = t >> 7;           // 0..3
        const int kk = t & (HH - 1);     // 0..127

        // layer 1 from LDS: pooled = xs @ Wg + bg
        float a1 = bg[kk];
        #pragma unroll 8
        for (int j = 0; j < HH; ++j) a1 += xs[bb * HH + j] * WL[j * HH + kk];
        ys[t] = a1;
        __syncthreads();

        // swap in W1 (L3-warm) and run layer 2
        for (int i = t; i < HH * HH / 4; i += WTHR) wlv[i] = w1v[i];
        __syncthreads();
        float a2 = b1[kk];
        #pragma unroll 8
        for (int j = 0; j < HH; ++j) a2 += ys[bb * HH + j] * WL[j * HH + kk];
        a2 = fmaxf(a2, 0.0f);
        red[t] = a2 * W2[kk];
        __syncthreads();

        // tree-reduce 128 -> 1 per batch
        #pragma unroll
        for (int off = HH / 2; off > 0; off >>= 1) {
            if (kk < off) red[bb * HH + kk] += red[bb * HH + kk + off];
            __syncthreads();
        }
        if (kk == 0) out[bb] = red[bb * HH] + b2[0];
        return;
    }

    // ---- worker blocks: chunk c = blockIdx.x - 1 ----
    const int c = blockIdx.x - 1;
    const int n0 = c * PER;
    const int n1 = min(NN, n0 + PER);
    const int cnt = n1 - n0;             // may be <= 0 for the last blocks
    float* vsec = v + (size_t)(c & (NSEC - 1)) * (NB * HH);

    if (cnt > 0) {
        // prologue: wpart[i][s] = sum of 8 ps rows (slice s) at node n0+i
        for (int idx = t; idx < cnt * 8; idx += WTHR) {
            const int i = idx >> 3, s = idx & 7;
            const int n = n0 + i;
            float a = 0.0f;
            #pragma unroll
            for (int u = 0; u < 8; ++u) a += ps[(size_t)(s * 8 + u) * NN + n];
            wpart[i][s] = a;
        }
        __syncthreads();
        for (int i = t; i < cnt; i += WTHR) {
            float a = 0.0f;
            #pragma unroll
            for (int s = 0; s < 8; ++s) a += wpart[i][s];
            const float di = dinv[n0 + i];
            wl[i] = di * (di + a);
        }
        __syncthreads();

        const int g = t >> 5;        // node subgroup 0..15
        const int q = t & 31;
        const float* base = (q < 16) ? (fa + (size_t)q * 4)
                                     : (fb + (size_t)(q - 16) * 4);

        float4 acc[NB];
        #pragma unroll
        for (int b = 0; b < NB; ++b) acc[b] = make_float4(0.f, 0.f, 0.f, 0.f);

        int n = n0 + g;
        // main: 4 nodes x 4 batches = 16 independent float4 loads in flight
        for (; n + 48 < n1; n += 64) {
            const float w0 = wl[n - n0];
            const float w1 = wl[n + 16 - n0];
            const float w2 = wl[n + 32 - n0];
            const float w3 = wl[n + 48 - n0];
            #pragma unroll
            for (int b = 0; b < NB; ++b) {
                const float* p = base + ((size_t)b * NN + n) * 64;
                float4 x0 = *reinterpret_cast<const float4*>(p);
                float4 x1 = *reinterpret_cast<const float4*>(p + 16 * 64);
                float4 x2 = *reinterpret_cast<const float4*>(p + 32 * 64);
                float4 x3 = *reinterpret_cast<const float4*>(p + 48 * 64);
                acc[b].x += w0 * x0.x + w1 * x1.x + w2 * x2.x + w3 * x3.x;
                acc[b].y += w0 * x0.y + w1 * x1.y + w2 * x2.y + w3 * x3.y;
                acc[b].z += w0 * x0.z + w1 * x1.z + w2 * x2.z + w3 * x3.z;
                acc[b].w += w0 * x0.w + w1 * x1.w + w2 * x2.w + w3 * x3.w;
            }
        }
        for (; n < n1; n += 16) {     // remainder (<= 3 nodes per g)
            const float wn = wl[n - n0];
            #pragma unroll
            for (int b = 0; b < NB; ++b) {
                float4 x = *reinterpret_cast<const float4*>(
                    base + ((size_t)b * NN + n) * 64);
                acc[b].x += wn * x.x; acc[b].y += wn * x.y;
                acc[b].z += wn * x.z; acc[b].w += wn * x.w;
            }
        }

        #pragma unroll
        for (int b = 0; b < NB; ++b) {
            smem[t] = acc[b];
            __syncthreads();
            if (t < 32) {    // wave 0 issues ALL of this block's v-atomics
                float4 r = smem[t];
                #pragma unroll
                for (int gg = 1; gg < 16; ++gg) {
                    float4 o = smem[gg * 32 + t];
                    r.x += o.x; r.y += o.y; r.z += o.z; r.w += o.w;
                }
                const int k = (t < 16) ? t * 4 : 64 + (t - 16) * 4;
                float* vb = vsec + b * HH + k;
                atomicAdd(vb + 0, r.x);
                atomicAdd(vb + 1, r.y);
                atomicAdd(vb + 2, r.z);
                atomicAdd(vb + 3, r.w);
            }
            __syncthreads();
        }
    }

    if (t == 0) {
        // wave 0 waits for its own v-atomics to reach the coherent point,
        // then signals via the hierarchical counter. No fences anywhere.
        asm volatile("s_waitcnt vmcnt(0)" ::: "memory");
        int old = atomicAdd(&sub[c & (NSEC - 1)], 1);
        if (old == (CHUNKS / NSEC) - 1) atomicAdd(master, 1);
    }
}

extern "C" void kernel_launch(void* const* d_in, const int* in_sizes, int n_in,
                              void* d_out, int out_size, void* d_ws, size_t ws_size,
                              hipStream_t stream) {
    const float* fa = (const float*)d_in[0];   // [B,N,64]
    const float* fb = (const float*)d_in[1];   // [B,N,64]
    const int*   ei = (const int*)d_in[2];     // [2,E]
    const float* Wg = (const float*)d_in[3];   // [H,H]
    const float* bg = (const float*)d_in[4];   // [H]
    const float* W1 = (const float*)d_in[5];   // [H,H]
    const float* b1 = (const float*)d_in[6];   // [H]
    const float* W2 = (const float*)d_in[7];   // [H,1]
    const float* b2 = (const float*)d_in[8];   // [1]
    float* out = (float*)d_out;

    const int* src = ei;
    const int* dst = ei + NE;

    float* ws   = (float*)d_ws;
    float* pdeg = ws + OFF_PDEG;
    float* dinv = ws + OFF_DINV;
    float* ps   = ws + OFF_PS;
    float* v    = ws + OFF_V;
    int*   cnts = (int*)(ws + OFF_CNT);

    deg_hist_kernel<<<EBLK, HTHR, 0, stream>>>(dst, pdeg);

    reduce_deg_kernel<<<RB, 256, 0, stream>>>(pdeg, dinv, v, cnts);

    s_hist_kernel<<<EBLK, HTHR, 0, stream>>>(src, dst, dinv, ps);

    wsum_mlp_kernel<<<CHUNKS + 1, WTHR, 0, stream>>>(fa, fb, dinv, ps,
                                                     Wg, bg, W1, b1, W2, b2,
                                                     v, cnts, out);
}